// Round 10
// baseline (194.808 us; speedup 1.0000x reference)
//
#include <hip/hip_runtime.h>

// Problem constants (match reference)
#define N_NODES    4096
#define N_EDGES    65536
#define BATCH      8
#define EDGE_TYPES 2
#define UNITS      64

// Clang-native vector types: __builtin_nontemporal_* requires these
// (HIP_vector_type wrappers are rejected).
typedef int   vint2   __attribute__((ext_vector_type(2)));
typedef int   vint4   __attribute__((ext_vector_type(4)));
typedef float vfloat4 __attribute__((ext_vector_type(4)));

// Workspace layout (all int32):
//   idx   [N_EDGES]    : target node of each edge
//   start [N_NODES+1]  : CSR row starts
//   pos   [N_NODES]    : CSR fill cursors (seeded to start[n])
//   csr   [N_EDGES]    : edge ids grouped by target node
#define WS_IDX   0
#define WS_START (WS_IDX + N_EDGES)
#define WS_POS   (WS_START + N_NODES + 1)
#define WS_CSR   (WS_POS + N_NODES)

// ---------------------------------------------------------------------------
// 1) recover edge target indices from the dense one-hot [E, N] buffer.
//    Bytes after each row's single 1.0 are informationless — scan only UNTIL
//    found. One wave per row; up to 32 rounds of 128 floats (1 int2 = 8 B
//    per lane); __any-ballot early exit. Expected read fraction
//    (1 + 128/4096)/2 = 51.6% (floor: 50%). 8 waves/SIMD interleave the
//    ~16.5-round serial chain per row -> stays HBM-BW-bound.
//    Data-dependent but replay-deterministic. Nontemporal read-once stream.
// ---------------------------------------------------------------------------
__global__ void extract_idx_kernel(const vint2* __restrict__ tgt,
                                   int* __restrict__ idx) {
    const int gt   = blockIdx.x * blockDim.x + threadIdx.x;
    const int lane = gt & 63;
    const int w    = gt >> 6;                       // global wave id
    const int NW   = (gridDim.x * blockDim.x) >> 6; // total waves (8192)

    for (int e = w; e < N_EDGES; e += NW) {
        const vint2* row = tgt + (size_t)e * (N_NODES / 2);   // 2048 int2s
        int found = -1;
        #pragma unroll 1
        for (int k = 0; k < 32; ++k) {
            const int ci = k * 64 + lane;           // int2 index within row
            const vint2 a = __builtin_nontemporal_load(&row[ci]);
            int pos = -1;
            if (a.x | a.y) {
                pos = (ci << 1) + (a.x ? 0 : 1);
            }
            if (__any(pos >= 0)) { found = pos; break; }
        }
        if (found >= 0) idx[e] = found;             // exactly one lane writes
    }
}

// ---------------------------------------------------------------------------
// 2) single-block: LDS histogram of idx -> per-node degree, then exclusive
//    prefix scan -> start[0..4096]; also seeds pos[n] = start[n].
// ---------------------------------------------------------------------------
__global__ void hist_scan_kernel(const int* __restrict__ idx,
                                 int* __restrict__ start,
                                 int* __restrict__ pos) {
    __shared__ int hist[N_NODES];
    __shared__ int wave_sums[16];
    const int t = threadIdx.x;          // 0..1023
    const int lane = t & 63;
    const int wid = t >> 6;             // 16 waves

    for (int i = t; i < N_NODES; i += 1024) hist[i] = 0;
    __syncthreads();

    const int4* idx4 = (const int4*)idx;
    for (int i = t; i < N_EDGES / 4; i += 1024) {
        const int4 v = idx4[i];
        atomicAdd(&hist[v.x], 1);
        atomicAdd(&hist[v.y], 1);
        atomicAdd(&hist[v.z], 1);
        atomicAdd(&hist[v.w], 1);
    }
    __syncthreads();

    const int4 c = ((const int4*)hist)[t];
    const int local = c.x + c.y + c.z + c.w;

    // inclusive scan of per-thread sums within the wave
    int v = local;
    for (int off = 1; off < 64; off <<= 1) {
        const int u = __shfl_up(v, off, 64);
        if (lane >= off) v += u;
    }
    if (lane == 63) wave_sums[wid] = v;
    __syncthreads();
    if (wid == 0 && lane < 16) {
        int ws = wave_sums[lane];
        for (int off = 1; off < 16; off <<= 1) {
            const int u = __shfl_up(ws, off, 64);
            if (lane >= off) ws += u;
        }
        wave_sums[lane] = ws;           // inclusive wave totals
    }
    __syncthreads();

    const int wave_excl = (wid == 0) ? 0 : wave_sums[wid - 1];
    const int thread_excl = wave_excl + (v - local);

    int4 s;
    s.x = thread_excl;
    s.y = s.x + c.x;
    s.z = s.y + c.y;
    s.w = s.z + c.z;
    ((int4*)start)[t] = s;
    ((int4*)pos)[t] = s;                // seed cursors
    if (t == 1023) start[N_NODES] = s.w + c.w;   // total = N_EDGES
}

// ---------------------------------------------------------------------------
// 3) fill CSR: group edge ids by target node (pos pre-seeded with start).
// ---------------------------------------------------------------------------
__global__ void fill_csr_kernel(const int* __restrict__ idx,
                                int* __restrict__ pos,
                                int* __restrict__ csr) {
    const int e = blockIdx.x * blockDim.x + threadIdx.x;
    if (e < N_EDGES) {
        const int n = idx[e];
        const int p = atomicAdd(&pos[n], 1);
        csr[p] = e;
    }
}

// ---------------------------------------------------------------------------
// 4) gather: one WAVE per (n, b_high); lane = (b_low, u4). Edge loop is
//    wave-uniform (bounds scalarized, csr[j] broadcast). 4-edge unroll:
//    16 independent 16 B loads in flight per thread — at the random-256B
//    DRAM ceiling (~4.6 TB/s; >256 B contiguity structurally impossible
//    since a node's edges are random e, and the harness's 4.3 GB poison
//    fills wipe L3 residency between replays). Store nt.
// ---------------------------------------------------------------------------
__global__ void gather_kernel(const vfloat4* __restrict__ msgs,
                              const int* __restrict__ csr,
                              const int* __restrict__ start,
                              vfloat4* __restrict__ out) {
    const int gt = blockIdx.x * blockDim.x + threadIdx.x;  // 0 .. 524,287
    const int lane = gt & 63;
    const int w = gt >> 6;             // wave id: 0 .. 8191
    const int n  = w >> 1;             // node (wave-uniform)
    const int b  = ((w & 1) << 2) | (lane >> 4);   // batch 0..7
    const int u4 = lane & 15;

    const int j0 = __builtin_amdgcn_readfirstlane(start[n]);
    const int j1 = __builtin_amdgcn_readfirstlane(start[n + 1]);

    const vfloat4* m0 = msgs + (size_t)(b * EDGE_TYPES) * N_EDGES * (UNITS / 4);
    const vfloat4* m1 = m0 + (size_t)N_EDGES * (UNITS / 4);

    vfloat4 acc0 = (vfloat4)(0.f);
    vfloat4 acc1 = (vfloat4)(0.f);
    vfloat4 acc2 = (vfloat4)(0.f);
    vfloat4 acc3 = (vfloat4)(0.f);
    int j = j0;
    for (; j + 4 <= j1; j += 4) {
        const int e0 = csr[j];
        const int e1 = csr[j + 1];
        const int e2 = csr[j + 2];
        const int e3 = csr[j + 3];
        const vfloat4 x0 = m0[e0 * (UNITS / 4) + u4];
        const vfloat4 y0 = m1[e0 * (UNITS / 4) + u4];
        const vfloat4 x1 = m0[e1 * (UNITS / 4) + u4];
        const vfloat4 y1 = m1[e1 * (UNITS / 4) + u4];
        const vfloat4 x2 = m0[e2 * (UNITS / 4) + u4];
        const vfloat4 y2 = m1[e2 * (UNITS / 4) + u4];
        const vfloat4 x3 = m0[e3 * (UNITS / 4) + u4];
        const vfloat4 y3 = m1[e3 * (UNITS / 4) + u4];
        acc0 += x0 + y0;
        acc1 += x1 + y1;
        acc2 += x2 + y2;
        acc3 += x3 + y3;
    }
    for (; j < j1; ++j) {
        const int e0 = csr[j];
        const vfloat4 x0 = m0[e0 * (UNITS / 4) + u4];
        const vfloat4 y0 = m1[e0 * (UNITS / 4) + u4];
        acc0 += x0 + y0;
    }
    acc0 += acc1;
    acc2 += acc3;
    acc0 += acc2;
    __builtin_nontemporal_store(acc0, &out[((b * N_NODES + n) << 4) + u4]);
}

extern "C" void kernel_launch(void* const* d_in, const int* in_sizes, int n_in,
                              void* d_out, int out_size, void* d_ws, size_t ws_size,
                              hipStream_t stream) {
    const vfloat4* msgs = (const vfloat4*)d_in[0]; // [B, T, E, U] fp32
    const vint2*   tgt  = (const vint2*)d_in[1];   // [E, N] fp32 one-hot (bitwise)
    vfloat4* out = (vfloat4*)d_out;                // [B, 1, N, U] fp32

    int* ws    = (int*)d_ws;
    int* idx   = ws + WS_IDX;
    int* start = ws + WS_START;
    int* pos   = ws + WS_POS;
    int* csr   = ws + WS_CSR;

    // 1) recover indices: wave-per-row early-exit scan, 128-float rounds
    //    (~0.55 GB expected read)
    extract_idx_kernel<<<2048, 256, 0, stream>>>(tgt, idx);

    // 2) histogram + prefix scan -> CSR row starts + cursors (1 block)
    hist_scan_kernel<<<1, 1024, 0, stream>>>(idx, start, pos);

    // 3) group edges by node
    fill_csr_kernel<<<N_EDGES / 256, 256, 0, stream>>>(idx, pos, csr);

    // 4) gather + fused type-sum (reads 268 MB, writes 8 MiB nt)
    const int total_threads = BATCH * N_NODES * (UNITS / 4);  // 524,288
    gather_kernel<<<total_threads / 256, 256, 0, stream>>>(msgs, csr, start, out);
}

// Round 11
// 166.269 us; speedup vs baseline: 1.1716x; 1.1716x over previous
//
#include <hip/hip_runtime.h>

// Problem constants (match reference)
#define N_NODES    4096
#define N_EDGES    65536
#define BATCH      8
#define EDGE_TYPES 2
#define UNITS      64

// Clang-native vector types: __builtin_nontemporal_* requires these
// (HIP_vector_type wrappers are rejected).
typedef int   vint4   __attribute__((ext_vector_type(4)));
typedef float vfloat4 __attribute__((ext_vector_type(4)));

// Workspace layout (all int32):
//   idx   [N_EDGES]    : target node of each edge
//   start [N_NODES+1]  : CSR row starts
//   pos   [N_NODES]    : CSR fill cursors (seeded to start[n])
//   csr   [N_EDGES]    : edge ids grouped by target node
#define WS_IDX   0
#define WS_START (WS_IDX + N_EDGES)
#define WS_POS   (WS_START + N_NODES + 1)
#define WS_CSR   (WS_POS + N_NODES)

// ---------------------------------------------------------------------------
// 1) recover edge target indices from the dense one-hot [E, N] buffer.
//    Bytes after each row's single 1.0 are informationless — scan only UNTIL
//    found. One wave per row; up to 16 rounds of 256 floats (1 int4 = 16 B
//    per lane); __any-ballot early exit. Expected read fraction
//    (1 + 256/4096)/2 = 53.1% -> ~0.57 GB instead of 1.07 GB.
//    MEASURED OPTIMUM of the round-size family: 512-float rounds read 3%
//    more (175.7 µs total); 128-float rounds double the serial round chain
//    and halve bytes/instruction -> latency/issue-bound (194.8 µs total).
//    Data-dependent but replay-deterministic. Nontemporal read-once stream.
// ---------------------------------------------------------------------------
__global__ void extract_idx_kernel(const vint4* __restrict__ tgt,
                                   int* __restrict__ idx) {
    const int gt   = blockIdx.x * blockDim.x + threadIdx.x;
    const int lane = gt & 63;
    const int w    = gt >> 6;                       // global wave id
    const int NW   = (gridDim.x * blockDim.x) >> 6; // total waves (8192)

    for (int e = w; e < N_EDGES; e += NW) {
        const vint4* row = tgt + (size_t)e * (N_NODES / 4);   // 1024 int4s
        int found = -1;
        #pragma unroll 1
        for (int k = 0; k < 16; ++k) {
            const int ci = k * 64 + lane;           // int4 index within row
            const vint4 a = __builtin_nontemporal_load(&row[ci]);
            int pos = -1;
            if ((a.x | a.y) | (a.z | a.w)) {
                pos = (ci << 2) + (a.x ? 0 : a.y ? 1 : a.z ? 2 : 3);
            }
            if (__any(pos >= 0)) { found = pos; break; }
        }
        if (found >= 0) idx[e] = found;             // exactly one lane writes
    }
}

// ---------------------------------------------------------------------------
// 2) single-block: LDS histogram of idx -> per-node degree, then exclusive
//    prefix scan -> start[0..4096]; also seeds pos[n] = start[n].
// ---------------------------------------------------------------------------
__global__ void hist_scan_kernel(const int* __restrict__ idx,
                                 int* __restrict__ start,
                                 int* __restrict__ pos) {
    __shared__ int hist[N_NODES];
    __shared__ int wave_sums[16];
    const int t = threadIdx.x;          // 0..1023
    const int lane = t & 63;
    const int wid = t >> 6;             // 16 waves

    for (int i = t; i < N_NODES; i += 1024) hist[i] = 0;
    __syncthreads();

    const int4* idx4 = (const int4*)idx;
    for (int i = t; i < N_EDGES / 4; i += 1024) {
        const int4 v = idx4[i];
        atomicAdd(&hist[v.x], 1);
        atomicAdd(&hist[v.y], 1);
        atomicAdd(&hist[v.z], 1);
        atomicAdd(&hist[v.w], 1);
    }
    __syncthreads();

    const int4 c = ((const int4*)hist)[t];
    const int local = c.x + c.y + c.z + c.w;

    // inclusive scan of per-thread sums within the wave
    int v = local;
    for (int off = 1; off < 64; off <<= 1) {
        const int u = __shfl_up(v, off, 64);
        if (lane >= off) v += u;
    }
    if (lane == 63) wave_sums[wid] = v;
    __syncthreads();
    if (wid == 0 && lane < 16) {
        int ws = wave_sums[lane];
        for (int off = 1; off < 16; off <<= 1) {
            const int u = __shfl_up(ws, off, 64);
            if (lane >= off) ws += u;
        }
        wave_sums[lane] = ws;           // inclusive wave totals
    }
    __syncthreads();

    const int wave_excl = (wid == 0) ? 0 : wave_sums[wid - 1];
    const int thread_excl = wave_excl + (v - local);

    int4 s;
    s.x = thread_excl;
    s.y = s.x + c.x;
    s.z = s.y + c.y;
    s.w = s.z + c.z;
    ((int4*)start)[t] = s;
    ((int4*)pos)[t] = s;                // seed cursors
    if (t == 1023) start[N_NODES] = s.w + c.w;   // total = N_EDGES
}

// ---------------------------------------------------------------------------
// 3) fill CSR: group edge ids by target node (pos pre-seeded with start).
// ---------------------------------------------------------------------------
__global__ void fill_csr_kernel(const int* __restrict__ idx,
                                int* __restrict__ pos,
                                int* __restrict__ csr) {
    const int e = blockIdx.x * blockDim.x + threadIdx.x;
    if (e < N_EDGES) {
        const int n = idx[e];
        const int p = atomicAdd(&pos[n], 1);
        csr[p] = e;
    }
}

// ---------------------------------------------------------------------------
// 4) gather: one WAVE per (n, b_high); lane = (b_low, u4). Edge loop is
//    wave-uniform (bounds scalarized, csr[j] broadcast). 4-edge unroll:
//    16 independent 16 B loads in flight per thread — at the random-256B
//    DRAM ceiling (~4.6 TB/s; >256 B contiguity structurally impossible
//    since a node's edges are random e). msgs loads PLAIN CACHED (partial
//    L3 benefit measured ~4 µs). Output store nt (write-once).
// ---------------------------------------------------------------------------
__global__ void gather_kernel(const vfloat4* __restrict__ msgs,
                              const int* __restrict__ csr,
                              const int* __restrict__ start,
                              vfloat4* __restrict__ out) {
    const int gt = blockIdx.x * blockDim.x + threadIdx.x;  // 0 .. 524,287
    const int lane = gt & 63;
    const int w = gt >> 6;             // wave id: 0 .. 8191
    const int n  = w >> 1;             // node (wave-uniform)
    const int b  = ((w & 1) << 2) | (lane >> 4);   // batch 0..7
    const int u4 = lane & 15;

    const int j0 = __builtin_amdgcn_readfirstlane(start[n]);
    const int j1 = __builtin_amdgcn_readfirstlane(start[n + 1]);

    const vfloat4* m0 = msgs + (size_t)(b * EDGE_TYPES) * N_EDGES * (UNITS / 4);
    const vfloat4* m1 = m0 + (size_t)N_EDGES * (UNITS / 4);

    vfloat4 acc0 = (vfloat4)(0.f);
    vfloat4 acc1 = (vfloat4)(0.f);
    vfloat4 acc2 = (vfloat4)(0.f);
    vfloat4 acc3 = (vfloat4)(0.f);
    int j = j0;
    for (; j + 4 <= j1; j += 4) {
        const int e0 = csr[j];
        const int e1 = csr[j + 1];
        const int e2 = csr[j + 2];
        const int e3 = csr[j + 3];
        const vfloat4 x0 = m0[e0 * (UNITS / 4) + u4];
        const vfloat4 y0 = m1[e0 * (UNITS / 4) + u4];
        const vfloat4 x1 = m0[e1 * (UNITS / 4) + u4];
        const vfloat4 y1 = m1[e1 * (UNITS / 4) + u4];
        const vfloat4 x2 = m0[e2 * (UNITS / 4) + u4];
        const vfloat4 y2 = m1[e2 * (UNITS / 4) + u4];
        const vfloat4 x3 = m0[e3 * (UNITS / 4) + u4];
        const vfloat4 y3 = m1[e3 * (UNITS / 4) + u4];
        acc0 += x0 + y0;
        acc1 += x1 + y1;
        acc2 += x2 + y2;
        acc3 += x3 + y3;
    }
    for (; j < j1; ++j) {
        const int e0 = csr[j];
        const vfloat4 x0 = m0[e0 * (UNITS / 4) + u4];
        const vfloat4 y0 = m1[e0 * (UNITS / 4) + u4];
        acc0 += x0 + y0;
    }
    acc0 += acc1;
    acc2 += acc3;
    acc0 += acc2;
    __builtin_nontemporal_store(acc0, &out[((b * N_NODES + n) << 4) + u4]);
}

extern "C" void kernel_launch(void* const* d_in, const int* in_sizes, int n_in,
                              void* d_out, int out_size, void* d_ws, size_t ws_size,
                              hipStream_t stream) {
    const vfloat4* msgs = (const vfloat4*)d_in[0]; // [B, T, E, U] fp32
    const vint4*   tgt  = (const vint4*)d_in[1];   // [E, N] fp32 one-hot (bitwise)
    vfloat4* out = (vfloat4*)d_out;                // [B, 1, N, U] fp32

    int* ws    = (int*)d_ws;
    int* idx   = ws + WS_IDX;
    int* start = ws + WS_START;
    int* pos   = ws + WS_POS;
    int* csr   = ws + WS_CSR;

    // 1) recover indices: wave-per-row early-exit scan, 256-float rounds
    //    (~0.57 GB expected read) — measured optimum round size
    extract_idx_kernel<<<2048, 256, 0, stream>>>(tgt, idx);

    // 2) histogram + prefix scan -> CSR row starts + cursors (1 block)
    hist_scan_kernel<<<1, 1024, 0, stream>>>(idx, start, pos);

    // 3) group edges by node
    fill_csr_kernel<<<N_EDGES / 256, 256, 0, stream>>>(idx, pos, csr);

    // 4) gather + fused type-sum (reads 268 MB, writes 8 MiB nt)
    const int total_threads = BATCH * N_NODES * (UNITS / 4);  // 524,288
    gather_kernel<<<total_threads / 256, 256, 0, stream>>>(msgs, csr, start, out);
}